// Round 4
// baseline (129.503 us; speedup 1.0000x reference)
//
#include <hip/hip_runtime.h>
#include <math.h>

// Problem constants: B=4, H=W=1024, GH=GW=16, GD=8, C=12
// ws layout: gridbuf[((b*16+gh)*16+gw)*96 + z*12 + c], then params[81]
// params: [w_r x16][w_g x16][w_b x16][bias x16][g2w*log2e x16][g2b*log2e]

#define GRIDBUF_FLOATS (4 * 16 * 16 * 96)
#define CELL_STRIDE 100   // padded from 96: banks shift by 4 per wc

typedef float  f4 __attribute__((ext_vector_type(4)));
typedef int    i4 __attribute__((ext_vector_type(4)));
typedef float  f2 __attribute__((ext_vector_type(2)));

__device__ inline f4 splat4(float x) { f4 v = {x, x, x, x}; return v; }
__device__ inline f2 splat2(float x) { f2 v; v.x = x; v.y = x; return v; }

// packed tanh on a quad: t = sign(x) * (1 - 2/(exp2(2*log2e*|x|)+1))
__device__ inline f4 fast_tanh4(f4 x) {
    f4 ax = __builtin_elementwise_abs(x);
    f4 xx = ax * splat4(2.88539008178f);      // 2*log2(e)
    f4 e;
    e.x = __builtin_amdgcn_exp2f(xx.x);
    e.y = __builtin_amdgcn_exp2f(xx.y);
    e.z = __builtin_amdgcn_exp2f(xx.z);
    e.w = __builtin_amdgcn_exp2f(xx.w);
    f4 ep1 = e + splat4(1.0f);
    f4 r;
    r.x = __builtin_amdgcn_rcpf(ep1.x);
    r.y = __builtin_amdgcn_rcpf(ep1.y);
    r.z = __builtin_amdgcn_rcpf(ep1.z);
    r.w = __builtin_amdgcn_rcpf(ep1.w);
    f4 t = splat4(1.0f) - (r + r);            // in [0,1], e=inf -> t=1
    i4 sgn = __builtin_bit_cast(i4, x) &
             (i4){(int)0x80000000, (int)0x80000000, (int)0x80000000, (int)0x80000000};
    return __builtin_bit_cast(f4, __builtin_bit_cast(i4, t) | sgn);
}

// ---------------- Kernel 1: grid coefficients + folded guide params ----------
__global__ __launch_bounds__(128) void coeff_kernel(
    const float* __restrict__ lf,    // (B,64,16,16)
    const float* __restrict__ gf,    // (B,64)
    const float* __restrict__ fw,    // (96,64)
    const float* __restrict__ fb,    // (96,)
    const float* __restrict__ g1w,   // (16,3)
    const float* __restrict__ g1b,   // (16,)
    const float* __restrict__ bng,
    const float* __restrict__ bnb,
    const float* __restrict__ bnm,
    const float* __restrict__ bnv,
    const float* __restrict__ g2w,   // (1,16)
    const float* __restrict__ g2b,   // (1,)
    float* __restrict__ gridbuf,     // (B,16,16,96)
    float* __restrict__ params)      // 81 floats
{
    __shared__ float fused[64];
    const int blk = blockIdx.x;       // b*256 + pos
    const int b   = blk >> 8;
    const int pos = blk & 255;
    const int t   = threadIdx.x;

    if (t < 64) {
        float v = lf[(b * 64 + t) * 256 + pos] + gf[b * 64 + t];
        fused[t] = v > 0.0f ? v : 0.0f;
    }
    __syncthreads();

    if (t < 96) {
        float acc = fb[t];
        const float* wrow = fw + t * 64;
#pragma unroll
        for (int i = 0; i < 64; ++i) acc = fmaf(wrow[i], fused[i], acc);
        gridbuf[blk * 96 + t] = acc;
    }

    if (blk == 0 && t >= 96 && t < 112) {
        int k = t - 96;
        float a = bng[k] * rsqrtf(bnv[k] + 1e-5f);
        params[k]      = g1w[k * 3 + 0] * a;
        params[16 + k] = g1w[k * 3 + 1] * a;
        params[32 + k] = g1w[k * 3 + 2] * a;
        params[48 + k] = (g1b[k] - bnm[k]) * a + bnb[k];
        // fold log2(e) into the output layer so the device sigmoid uses exp2
        params[64 + k] = g2w[k] * 1.44269504f;
        if (k == 0) params[80] = g2b[0] * 1.44269504f;
    }
}

// ---------------- Kernel 2: guide + bilateral slice + apply + tanh -----------
// 4096 blocks x 256 threads: one block = ONE image row, 4 px/thread.
// 16B/lane loads+stores (coalescing sweet spot). Fill stages all 16 w-cells
// h-lerped into LDS (384 float4 ops over 256 threads; 128 threads do two).
// A 4-aligned pixel quad never straddles a w-cell boundary (boundaries at
// x == 32 mod 64), so w0i/wc0/wc1 are shared by all 4 pixels of a thread.
__global__ __launch_bounds__(256) void slice_apply_kernel(
    const float* __restrict__ fullres,  // (B,3,1024,1024)
    const float* __restrict__ gridbuf,  // (B,16,16,96)
    const float* __restrict__ params,   // 81 floats (uniform -> s_load)
    float* __restrict__ out)            // (B,3,1024,1024)
{
    __shared__ __align__(16) float hrow[16 * CELL_STRIDE];  // padded h-lerped row

    const int t   = threadIdx.x;
    const int blk = blockIdx.x;
    const int b   = blk >> 10;
    const int y   = blk & 1023;

    const int xb      = t << 2;                  // 4 pixels per thread
    const int pixbase = (y << 10) + xb;
    const int planeB  = (b * 3) << 20;

    // issue pixel loads early (in flight during fill + barrier)
    f4 rr = *(const f4*)(fullres + planeB + (0 << 20) + pixbase);
    f4 gg = *(const f4*)(fullres + planeB + (1 << 20) + pixbase);
    f4 bb = *(const f4*)(fullres + planeB + (2 << 20) + pixbase);

    // ---- fill: all 16 cells h-lerped for this row ----
    {
        const int h0i  = (y < 32) ? -1 : ((y - 32) >> 6);
        const float fh = ((float)y * 0.015625f + (0.0078125f - 0.5f)) - (float)h0i;
        const int hc0  = h0i < 0 ? 0 : h0i;
        const int hc1  = (h0i + 1) > 15 ? 15 : (h0i + 1);
        const float* row0 = gridbuf + (b * 256 + hc0 * 16) * 96;
        const float* row1 = gridbuf + (b * 256 + hc1 * 16) * 96;
        const float wfh0 = 1.0f - fh;

        {
            const int i  = t << 2;               // floats 0..1023
            const int wc = i / 96;
            const int rm = i - wc * 96;
            f4 a = *(const f4*)(row0 + i);
            f4 c = *(const f4*)(row1 + i);
            f4 r = __builtin_elementwise_fma(a, splat4(wfh0), c * splat4(fh));
            *(f4*)(hrow + wc * CELL_STRIDE + rm) = r;
        }
        if (t < 128) {
            const int i  = (t + 256) << 2;       // floats 1024..1535
            const int wc = i / 96;
            const int rm = i - wc * 96;
            f4 a = *(const f4*)(row0 + i);
            f4 c = *(const f4*)(row1 + i);
            f4 r = __builtin_elementwise_fma(a, splat4(wfh0), c * splat4(fh));
            *(f4*)(hrow + wc * CELL_STRIDE + rm) = r;
        }
    }
    __syncthreads();

    // w cells: shared by all 4 pixels of the quad
    const int w0i = (xb < 32) ? -1 : ((xb - 32) >> 6);
    const int wc0 = w0i < 0 ? 0 : w0i;
    const int wc1 = (w0i + 1) > 15 ? 15 : (w0i + 1);
    const float fw0 = (float)xb * 0.015625f + (0.0078125f - 0.5f) - (float)w0i;
    const float* cell0 = hrow + wc0 * CELL_STRIDE;
    const float* cell1 = hrow + wc1 * CELL_STRIDE;

    // ---- guide MLP, packed across the pixel quad ----
    f4 acc = splat4(params[80]);
#pragma unroll
    for (int k = 0; k < 16; ++k) {
        f4 gk = __builtin_elementwise_fma(rr, splat4(params[k]),
                __builtin_elementwise_fma(gg, splat4(params[16 + k]),
                __builtin_elementwise_fma(bb, splat4(params[32 + k]),
                                          splat4(params[48 + k]))));
        gk = __builtin_elementwise_max(gk, splat4(0.0f));
        acc = __builtin_elementwise_fma(gk, splat4(params[64 + k]), acc);
    }
    // sigmoid (exp2 form, log2e pre-folded) -> z coordinate: zg = 8*sigma - 0.5
    f4 zg;
    zg.x = fmaf(8.0f, __builtin_amdgcn_rcpf(1.0f + __builtin_amdgcn_exp2f(-acc.x)), -0.5f);
    zg.y = fmaf(8.0f, __builtin_amdgcn_rcpf(1.0f + __builtin_amdgcn_exp2f(-acc.y)), -0.5f);
    zg.z = fmaf(8.0f, __builtin_amdgcn_rcpf(1.0f + __builtin_amdgcn_exp2f(-acc.z)), -0.5f);
    zg.w = fmaf(8.0f, __builtin_amdgcn_rcpf(1.0f + __builtin_amdgcn_exp2f(-acc.w)), -0.5f);

    f4 Rp, Gp, Bp;
#pragma unroll
    for (int px = 0; px < 4; ++px) {
        const float zgp = zg[px];
        int   z0 = (int)floorf(zgp);
        float fz = zgp - (float)z0;
        int zc0 = z0 < 0 ? 0 : z0;
        int zc1 = (z0 + 1) > 7 ? 7 : (z0 + 1);

        const float fw_ = fw0 + (float)px * 0.015625f;
        const float ww0 = 1.0f - fw_;
        const f2 W00 = splat2(ww0 * (1.0f - fz));
        const f2 W01 = splat2(ww0 * fz);
        const f2 W10 = splat2(fw_ * (1.0f - fz));
        const f2 W11 = splat2(fw_ * fz);

        const float4* p00 = (const float4*)(cell0 + zc0 * 12);
        const float4* p01 = (const float4*)(cell0 + zc1 * 12);
        const float4* p10 = (const float4*)(cell1 + zc0 * 12);
        const float4* p11 = (const float4*)(cell1 + zc1 * 12);

        f2 sa[6];   // channel-packed: {s0,s1}..{s10,s11}
#pragma unroll
        for (int q = 0; q < 3; ++q) {
            float4 a = p00[q], c = p01[q], d = p10[q], e = p11[q];
            f2 alo = (f2){a.x, a.y}, ahi = (f2){a.z, a.w};
            f2 clo = (f2){c.x, c.y}, chi = (f2){c.z, c.w};
            f2 dlo = (f2){d.x, d.y}, dhi = (f2){d.z, d.w};
            f2 elo = (f2){e.x, e.y}, ehi = (f2){e.z, e.w};
            sa[2 * q] =
                __builtin_elementwise_fma(alo, W00,
                __builtin_elementwise_fma(clo, W01,
                __builtin_elementwise_fma(dlo, W10, elo * W11)));
            sa[2 * q + 1] =
                __builtin_elementwise_fma(ahi, W00,
                __builtin_elementwise_fma(chi, W01,
                __builtin_elementwise_fma(dhi, W10, ehi * W11)));
        }

        const float rs = rr[px];
        const float gs = gg[px];
        const float bs = bb[px];
        Rp[px] = fmaf(rs, sa[0].x, fmaf(gs, sa[0].y, fmaf(bs, sa[1].x, sa[4].y)));
        Gp[px] = fmaf(rs, sa[1].y, fmaf(gs, sa[2].x, fmaf(bs, sa[2].y, sa[5].x)));
        Bp[px] = fmaf(rs, sa[3].x, fmaf(gs, sa[3].y, fmaf(bs, sa[4].x, sa[5].y)));
    }

    f4 tR = fast_tanh4(Rp);
    f4 tG = fast_tanh4(Gp);
    f4 tB = fast_tanh4(Bp);

    __builtin_nontemporal_store(tR, (f4*)(out + planeB + (0 << 20) + pixbase));
    __builtin_nontemporal_store(tG, (f4*)(out + planeB + (1 << 20) + pixbase));
    __builtin_nontemporal_store(tB, (f4*)(out + planeB + (2 << 20) + pixbase));
}

extern "C" void kernel_launch(void* const* d_in, const int* in_sizes, int n_in,
                              void* d_out, int out_size, void* d_ws, size_t ws_size,
                              hipStream_t stream) {
    const float* fullres = (const float*)d_in[0];
    const float* lf      = (const float*)d_in[1];
    const float* gf      = (const float*)d_in[2];
    const float* fw      = (const float*)d_in[3];
    const float* fb      = (const float*)d_in[4];
    const float* g1w     = (const float*)d_in[5];
    const float* g1b     = (const float*)d_in[6];
    const float* bng     = (const float*)d_in[7];
    const float* bnb     = (const float*)d_in[8];
    const float* bnm     = (const float*)d_in[9];
    const float* bnv     = (const float*)d_in[10];
    const float* g2w     = (const float*)d_in[11];
    const float* g2b     = (const float*)d_in[12];
    float* out = (float*)d_out;

    float* gridbuf = (float*)d_ws;
    float* params  = gridbuf + GRIDBUF_FLOATS;

    coeff_kernel<<<4 * 256, 128, 0, stream>>>(lf, gf, fw, fb, g1w, g1b,
                                              bng, bnb, bnm, bnv, g2w, g2b,
                                              gridbuf, params);
    slice_apply_kernel<<<4 * 1024, 256, 0, stream>>>(fullres, gridbuf, params, out);
}